// Round 1
// baseline (177.726 us; speedup 1.0000x reference)
//
#include <hip/hip_runtime.h>

#define VV 4
#define NN 4096
#define HH 128
#define CAP 64
#define CH 32      // chunks for column-sum reduction
#define GR 16      // rows per block in h1@w2 gemm
#define FR 16      // rows per block in fusion

// ---------------------------------------------------------------------------
// Kernel 1: scan dense adjacency -> per-row neighbor lists + dinv.
// 1 wave per row, 4 rows per 256-thread block. float4 streaming loads.
// Neighbor indices appended in ascending order via wave prefix-sum
// (deterministic).
// ---------------------------------------------------------------------------
__global__ __launch_bounds__(256) void k_build_csr(
    const float* __restrict__ adjs, int* __restrict__ nbr,
    int* __restrict__ cnt, float* __restrict__ dinv)
{
    int wave = threadIdx.x >> 6;
    int lane = threadIdx.x & 63;
    int r = blockIdx.x * 4 + wave;              // global row in [0, V*N)
    const float4* row = (const float4*)(adjs + (size_t)r * NN);
    int* out = nbr + (size_t)r * CAP;
    int base = 0;
    for (int c = 0; c < NN / 256; ++c) {
        float4 x = row[c * 64 + lane];
        int c0 = (x.x != 0.f), c1 = (x.y != 0.f), c2 = (x.z != 0.f), c3 = (x.w != 0.f);
        int cl = c0 + c1 + c2 + c3;
        // inclusive wave scan
        int s = cl;
        #pragma unroll
        for (int d = 1; d < 64; d <<= 1) {
            int y = __shfl_up(s, d, 64);
            if (lane >= d) s += y;
        }
        int pre = s - cl;
        int total = __shfl(s, 63, 64);
        int pos = base + pre;
        int e = c * 256 + lane * 4;
        if (c0 && pos < CAP) out[pos] = e;     pos += c0;
        if (c1 && pos < CAP) out[pos] = e + 1; pos += c1;
        if (c2 && pos < CAP) out[pos] = e + 2; pos += c2;
        if (c3 && pos < CAP) out[pos] = e + 3; pos += c3;
        base += total;
    }
    if (lane == 0) {
        cnt[r]  = base < CAP ? base : CAP;
        dinv[r] = rsqrtf((float)(base + 1));   // +1 self loop
    }
}

// ---------------------------------------------------------------------------
// Kernel 2: SpMM  out[v,i,:] = relu( dinv_i*( sum_{j in nbr(i)} dinv_j*feat[v,j,:]
//                                            + dinv_i*feat[v,i,:] ) + bias[v,:] )
// One block (128 threads = H) per row.
// ---------------------------------------------------------------------------
__global__ __launch_bounds__(128) void k_spmm(
    const float* __restrict__ feat, const float* __restrict__ bias,
    const int* __restrict__ nbr, const int* __restrict__ cnt,
    const float* __restrict__ dinv, float* __restrict__ out)
{
    int r = blockIdx.x;                 // [0, V*N)
    int v = r / NN;
    int h = threadIdx.x;
    __shared__ int   s_j[CAP];
    __shared__ float s_w[CAP];
    int n = cnt[r];
    float dr = dinv[r];
    if (h < n) {
        int j = nbr[(size_t)r * CAP + h];
        s_j[h] = j;
        s_w[h] = dinv[v * NN + j];
    }
    __syncthreads();
    float acc = dr * feat[(size_t)r * HH + h];          // self loop term
    for (int k = 0; k < n; ++k)
        acc += s_w[k] * feat[((size_t)(v * NN + s_j[k])) * HH + h];
    float val = dr * acc + bias[v * HH + h];
    out[(size_t)r * HH + h] = val > 0.f ? val : 0.f;
}

// ---------------------------------------------------------------------------
// Kernel 3: t = h1 @ w2   ([V,N,H] x [V,H,H]), 16 rows per block.
// ---------------------------------------------------------------------------
__global__ __launch_bounds__(128) void k_gemm_w2(
    const float* __restrict__ h1, const float* __restrict__ w2,
    float* __restrict__ t)
{
    const int bpv = NN / GR;            // blocks per view
    int v = blockIdx.x / bpv;
    int rbase = (blockIdx.x % bpv) * GR;
    int h = threadIdx.x;
    __shared__ float s_in[GR][HH];
    const float* src = h1 + ((size_t)v * NN + rbase) * HH;
    for (int idx = threadIdx.x; idx < GR * HH; idx += 128)
        ((float*)s_in)[idx] = src[idx];
    __syncthreads();
    float acc[GR];
    #pragma unroll
    for (int r = 0; r < GR; ++r) acc[r] = 0.f;
    const float* wv = w2 + (size_t)v * HH * HH;
    for (int k = 0; k < HH; ++k) {
        float wk = wv[k * HH + h];
        #pragma unroll
        for (int r = 0; r < GR; ++r) acc[r] += s_in[r][k] * wk;
    }
    float* dst = t + ((size_t)v * NN + rbase) * HH;
    #pragma unroll
    for (int r = 0; r < GR; ++r) dst[r * HH + h] = acc[r];
}

// ---------------------------------------------------------------------------
// Kernel 4: partial column sums of h2 for summaries (deterministic 2-stage).
// ---------------------------------------------------------------------------
__global__ __launch_bounds__(128) void k_colsum(
    const float* __restrict__ h2, float* __restrict__ part)
{
    int v = blockIdx.x / CH;
    int c = blockIdx.x % CH;
    int h = threadIdx.x;
    const int rows = NN / CH;           // 128
    const float* src = h2 + ((size_t)v * NN + c * rows) * HH;
    float acc = 0.f;
    for (int rr = 0; rr < rows; ++rr) acc += src[rr * HH + h];
    part[(size_t)blockIdx.x * HH + h] = acc;
}

// ---------------------------------------------------------------------------
// Kernel 5: finish summaries, attention MLP, softmax. Single block.
// ---------------------------------------------------------------------------
__global__ __launch_bounds__(256) void k_attn(
    const float* __restrict__ part, const float* __restrict__ wa1,
    const float* __restrict__ ba1, const float* __restrict__ wa2,
    const float* __restrict__ ba2, float* __restrict__ attn_out,
    float* __restrict__ attn_ws)
{
    __shared__ float s_sum[VV * HH];
    __shared__ float s_red[256];
    __shared__ float s_score[VV];
    for (int p = threadIdx.x; p < VV * HH; p += 256) {
        int v = p / HH, h = p % HH;
        float a = 0.f;
        for (int c = 0; c < CH; ++c) a += part[(size_t)(v * CH + c) * HH + h];
        s_sum[p] = a * (1.0f / NN);     // mean over N
    }
    __syncthreads();
    int v = threadIdx.x >> 6, u = threadIdx.x & 63;
    float a = ba1[u];
    for (int k = 0; k < HH; ++k) a += s_sum[v * HH + k] * wa1[k * 64 + u];
    s_red[threadIdx.x] = tanhf(a) * wa2[u];
    __syncthreads();
    if (threadIdx.x < VV) {
        float sc = ba2[0];
        for (int uu = 0; uu < 64; ++uu) sc += s_red[threadIdx.x * 64 + uu];
        s_score[threadIdx.x] = sc;
    }
    __syncthreads();
    if (threadIdx.x == 0) {
        float m = s_score[0];
        for (int i = 1; i < VV; ++i) m = fmaxf(m, s_score[i]);
        float e[VV], den = 0.f;
        for (int i = 0; i < VV; ++i) { e[i] = __expf(s_score[i] - m); den += e[i]; }
        for (int i = 0; i < VV; ++i) {
            float av = e[i] / den;
            attn_out[i] = av;
            attn_ws[i]  = av;
        }
    }
}

// ---------------------------------------------------------------------------
// Kernel 6: fusion MLP. 16 rows per block; fusion_in staged in LDS;
// wf1 (512KB) / wf2 (128KB) stream from L2.
// ---------------------------------------------------------------------------
__global__ __launch_bounds__(256) void k_fusion(
    const float* __restrict__ h2, const float* __restrict__ attn_ws,
    const float* __restrict__ wf1, const float* __restrict__ bf1,
    const float* __restrict__ wf2, const float* __restrict__ bf2,
    float* __restrict__ fused)
{
    __shared__ float s_in[FR][VV * HH];     // 16 x 512 = 32 KB
    __shared__ float s_hid[FR][2 * HH];     // 16 x 256 = 16 KB
    int nbase = blockIdx.x * FR;
    float at[VV];
    #pragma unroll
    for (int v = 0; v < VV; ++v) at[v] = attn_ws[v];
    for (int idx = threadIdx.x; idx < FR * VV * HH; idx += 256) {
        int r = idx / (VV * HH);
        int c = idx % (VV * HH);
        int v = c / HH, h = c % HH;
        s_in[r][c] = h2[((size_t)v * NN + nbase + r) * HH + h] * at[v];
    }
    __syncthreads();
    // GEMM1: hidden[r][j] = relu(sum_k in[r][k]*wf1[k][j] + bf1[j])
    int j = threadIdx.x;
    float acc[FR];
    #pragma unroll
    for (int r = 0; r < FR; ++r) acc[r] = 0.f;
    for (int k = 0; k < VV * HH; ++k) {
        float wk = wf1[(size_t)k * (2 * HH) + j];
        #pragma unroll
        for (int r = 0; r < FR; ++r) acc[r] += s_in[r][k] * wk;
    }
    float bj = bf1[j];
    #pragma unroll
    for (int r = 0; r < FR; ++r) {
        float hv = acc[r] + bj;
        s_hid[r][j] = hv > 0.f ? hv : 0.f;
    }
    __syncthreads();
    // GEMM2: fused[r][o] = sum_k hidden[r][k]*wf2[k][o] + bf2[o]
    int o = threadIdx.x & 127;
    int rb = (threadIdx.x >> 7) * (FR / 2);     // 0 or 8
    float acc2[FR / 2];
    #pragma unroll
    for (int r = 0; r < FR / 2; ++r) acc2[r] = 0.f;
    for (int k = 0; k < 2 * HH; ++k) {
        float wk = wf2[k * HH + o];
        #pragma unroll
        for (int r = 0; r < FR / 2; ++r) acc2[r] += s_hid[rb + r][k] * wk;
    }
    #pragma unroll
    for (int r = 0; r < FR / 2; ++r)
        fused[(size_t)(nbase + rb + r) * HH + o] = acc2[r] + bf2[o];
}

// ---------------------------------------------------------------------------
extern "C" void kernel_launch(void* const* d_in, const int* in_sizes, int n_in,
                              void* d_out, int out_size, void* d_ws, size_t ws_size,
                              hipStream_t stream)
{
    const float* adjs = (const float*)d_in[0];
    const float* w1   = (const float*)d_in[1];
    const float* b1   = (const float*)d_in[2];
    const float* w2   = (const float*)d_in[3];
    const float* b2   = (const float*)d_in[4];
    const float* wa1  = (const float*)d_in[5];
    const float* ba1  = (const float*)d_in[6];
    const float* wa2  = (const float*)d_in[7];
    const float* ba2  = (const float*)d_in[8];
    const float* wf1  = (const float*)d_in[9];
    const float* bf1  = (const float*)d_in[10];
    const float* wf2  = (const float*)d_in[11];
    const float* bf2  = (const float*)d_in[12];

    float* out   = (float*)d_out;
    float* fused = out;                        // [N, 128]
    float* attn  = out + (size_t)NN * HH;      // [V]
    float* h2    = attn + VV;                  // [V, N, H]

    char* w = (char*)d_ws;
    int*   nbr    = (int*)w;    w += (size_t)VV * NN * CAP * sizeof(int);
    int*   cnt    = (int*)w;    w += (size_t)VV * NN * sizeof(int);
    float* dinv   = (float*)w;  w += (size_t)VV * NN * sizeof(float);
    float* h1     = (float*)w;  w += (size_t)VV * NN * HH * sizeof(float);
    float* t      = (float*)w;  w += (size_t)VV * NN * HH * sizeof(float);
    float* part   = (float*)w;  w += (size_t)VV * CH * HH * sizeof(float);
    float* attnws = (float*)w;  w += (size_t)VV * sizeof(float);

    k_build_csr<<<VV * NN / 4, 256, 0, stream>>>(adjs, nbr, cnt, dinv);
    k_spmm<<<VV * NN, 128, 0, stream>>>(w1, b1, nbr, cnt, dinv, h1);
    k_gemm_w2<<<VV * NN / GR, 128, 0, stream>>>(h1, w2, t);
    k_spmm<<<VV * NN, 128, 0, stream>>>(t, b2, nbr, cnt, dinv, h2);
    k_colsum<<<VV * CH, 128, 0, stream>>>(h2, part);
    k_attn<<<1, 256, 0, stream>>>(part, wa1, ba1, wa2, ba2, attn, attnws);
    k_fusion<<<NN / FR, 256, 0, stream>>>(h2, attnws, wf1, bf1, wf2, bf2, fused);
}

// Round 3
// 153.817 us; speedup vs baseline: 1.1554x; 1.1554x over previous
//
#include <hip/hip_runtime.h>

#define VV 4
#define NN 4096
#define HH 128
#define CAP 64
#define CH 64      // chunks for column-sum reduction
#define GR 32      // rows per block in h1@w2 gemm
#define FR 16      // rows per block in fusion

typedef __attribute__((ext_vector_type(4))) float fvec4;   // nontemporal-loadable

// ---------------------------------------------------------------------------
// Kernel 1: scan dense adjacency -> per-row neighbor lists + dinv.
// 1 wave per row, 4 rows per 256-thread block. Nontemporal float4 loads.
// Positions via ballot+popcount (flat, no serial shuffle chain).
// ---------------------------------------------------------------------------
__global__ __launch_bounds__(256) void k_build_csr(
    const float* __restrict__ adjs, int* __restrict__ nbr,
    int* __restrict__ cnt, float* __restrict__ dinv)
{
    int wave = threadIdx.x >> 6;
    int lane = threadIdx.x & 63;
    int r = blockIdx.x * 4 + wave;              // global row in [0, V*N)
    const fvec4* row = (const fvec4*)(adjs + (size_t)r * NN);
    int* out = nbr + (size_t)r * CAP;
    unsigned long long lm = (1ull << lane) - 1ull;
    int base = 0;
    #pragma unroll 4
    for (int c = 0; c < NN / 256; ++c) {
        fvec4 x = __builtin_nontemporal_load(&row[c * 64 + lane]);
        int c0 = (x.x != 0.f), c1 = (x.y != 0.f), c2 = (x.z != 0.f), c3 = (x.w != 0.f);
        unsigned long long b0 = __ballot(c0), b1 = __ballot(c1);
        unsigned long long b2 = __ballot(c2), b3 = __ballot(c3);
        int pos = base + __popcll(b0 & lm) + __popcll(b1 & lm)
                       + __popcll(b2 & lm) + __popcll(b3 & lm);
        int e = c * 256 + lane * 4;
        if (c0 && pos < CAP) out[pos] = e;     pos += c0;
        if (c1 && pos < CAP) out[pos] = e + 1; pos += c1;
        if (c2 && pos < CAP) out[pos] = e + 2; pos += c2;
        if (c3 && pos < CAP) out[pos] = e + 3; pos += c3;
        base += __popcll(b0) + __popcll(b1) + __popcll(b2) + __popcll(b3);
    }
    if (lane == 0) {
        cnt[r]  = base < CAP ? base : CAP;
        dinv[r] = rsqrtf((float)(base + 1));   // +1 self loop
    }
}

// ---------------------------------------------------------------------------
// Kernel 2: SpMM  out[v,i,:] = relu( dinv_i*( sum_{j in nbr(i)} dinv_j*feat[v,j,:]
//                                            + dinv_i*feat[v,i,:] ) + bias[v,:] )
// One block (128 threads = H) per row.
// ---------------------------------------------------------------------------
__global__ __launch_bounds__(128) void k_spmm(
    const float* __restrict__ feat, const float* __restrict__ bias,
    const int* __restrict__ nbr, const int* __restrict__ cnt,
    const float* __restrict__ dinv, float* __restrict__ out)
{
    int r = blockIdx.x;                 // [0, V*N)
    int v = r >> 12;
    int h = threadIdx.x;
    __shared__ int   s_j[CAP];
    __shared__ float s_w[CAP];
    int n = cnt[r];
    float dr = dinv[r];
    if (h < n) {
        int j = nbr[(size_t)r * CAP + h];
        s_j[h] = j;
        s_w[h] = dinv[v * NN + j];
    }
    __syncthreads();
    float acc = dr * feat[(size_t)r * HH + h];          // self loop term
    #pragma unroll 4
    for (int k = 0; k < n; ++k)
        acc += s_w[k] * feat[((size_t)(v * NN + s_j[k])) * HH + h];
    float val = dr * acc + bias[v * HH + h];
    out[(size_t)r * HH + h] = val > 0.f ? val : 0.f;
}

// ---------------------------------------------------------------------------
// Kernel 3: t = h1 @ w2   ([V,N,H] x [V,H,H]).
// 32 rows/block, 256 threads, 4x4 register tile per thread, k-chunks of 4
// with ds_read_b128 (wave-uniform broadcast -> conflict-free).
// ---------------------------------------------------------------------------
__global__ __launch_bounds__(256) void k_gemm_w2(
    const float* __restrict__ h1, const float* __restrict__ w2,
    float* __restrict__ t)
{
    const int bpv = NN / GR;            // blocks per view
    int v = blockIdx.x / bpv;
    int rbase = (blockIdx.x % bpv) * GR;
    __shared__ float s_in[GR][HH];      // 16 KB
    const float4* src = (const float4*)(h1 + ((size_t)v * NN + rbase) * HH);
    for (int idx = threadIdx.x; idx < GR * HH / 4; idx += 256)
        ((float4*)s_in)[idx] = src[idx];
    __syncthreads();

    int r0 = (threadIdx.x >> 5) * 4;          // 0..28
    int c0 = (threadIdx.x & 31) * 4;          // 0..124
    const float* wv = w2 + (size_t)v * HH * HH;
    float acc[4][4];
    #pragma unroll
    for (int i = 0; i < 4; ++i)
        #pragma unroll
        for (int j = 0; j < 4; ++j) acc[i][j] = 0.f;

    for (int k = 0; k < HH; k += 4) {
        float4 a[4], w[4];
        #pragma unroll
        for (int i = 0; i < 4; ++i) a[i] = *(const float4*)&s_in[r0 + i][k];
        #pragma unroll
        for (int kk = 0; kk < 4; ++kk) w[kk] = *(const float4*)&wv[(size_t)(k + kk) * HH + c0];
        #pragma unroll
        for (int i = 0; i < 4; ++i) {
            #pragma unroll
            for (int j = 0; j < 4; ++j) {
                acc[i][j] += a[i].x * ((const float*)&w[0])[j];
                acc[i][j] += a[i].y * ((const float*)&w[1])[j];
                acc[i][j] += a[i].z * ((const float*)&w[2])[j];
                acc[i][j] += a[i].w * ((const float*)&w[3])[j];
            }
        }
    }
    float* dst = t + ((size_t)v * NN + rbase) * HH;
    #pragma unroll
    for (int i = 0; i < 4; ++i) {
        float4 o = { acc[i][0], acc[i][1], acc[i][2], acc[i][3] };
        *(float4*)&dst[(size_t)(r0 + i) * HH + c0] = o;
    }
}

// ---------------------------------------------------------------------------
// Kernel 4: partial column sums of h2 for summaries (deterministic 2-stage).
// ---------------------------------------------------------------------------
__global__ __launch_bounds__(128) void k_colsum(
    const float* __restrict__ h2, float* __restrict__ part)
{
    int v = blockIdx.x / CH;
    int c = blockIdx.x % CH;
    int h = threadIdx.x;
    const int rows = NN / CH;           // 64
    const float* src = h2 + ((size_t)v * NN + c * rows) * HH;
    float acc = 0.f;
    #pragma unroll 8
    for (int rr = 0; rr < rows; ++rr) acc += src[rr * HH + h];
    part[(size_t)blockIdx.x * HH + h] = acc;
}

// ---------------------------------------------------------------------------
// Kernel 5: finish summaries, attention MLP, softmax. Single block.
// ---------------------------------------------------------------------------
__global__ __launch_bounds__(256) void k_attn(
    const float* __restrict__ part, const float* __restrict__ wa1,
    const float* __restrict__ ba1, const float* __restrict__ wa2,
    const float* __restrict__ ba2, float* __restrict__ attn_out,
    float* __restrict__ attn_ws)
{
    __shared__ float s_sum[VV * HH];
    __shared__ float s_red[256];
    __shared__ float s_score[VV];
    for (int p = threadIdx.x; p < VV * HH; p += 256) {
        int v = p / HH, h = p % HH;
        float a = 0.f;
        for (int c = 0; c < CH; ++c) a += part[(size_t)(v * CH + c) * HH + h];
        s_sum[p] = a * (1.0f / NN);     // mean over N
    }
    __syncthreads();
    int v = threadIdx.x >> 6, u = threadIdx.x & 63;
    float a = ba1[u];
    for (int k = 0; k < HH; ++k) a += s_sum[v * HH + k] * wa1[k * 64 + u];
    s_red[threadIdx.x] = tanhf(a) * wa2[u];
    __syncthreads();
    if (threadIdx.x < VV) {
        float sc = ba2[0];
        for (int uu = 0; uu < 64; ++uu) sc += s_red[threadIdx.x * 64 + uu];
        s_score[threadIdx.x] = sc;
    }
    __syncthreads();
    if (threadIdx.x == 0) {
        float m = s_score[0];
        for (int i = 1; i < VV; ++i) m = fmaxf(m, s_score[i]);
        float e[VV], den = 0.f;
        for (int i = 0; i < VV; ++i) { e[i] = __expf(s_score[i] - m); den += e[i]; }
        for (int i = 0; i < VV; ++i) {
            float av = e[i] / den;
            attn_out[i] = av;
            attn_ws[i]  = av;
        }
    }
}

// ---------------------------------------------------------------------------
// Kernel 6: fusion MLP. 16 rows/block, 256 threads; register-tiled 4x4
// (GEMM1: 16x256 out) and 2x4 (GEMM2: 16x128 out); LDS reads are
// wave-uniform-broadcast ds_read_b128.
// ---------------------------------------------------------------------------
__global__ __launch_bounds__(256) void k_fusion(
    const float* __restrict__ h2, const float* __restrict__ attn_ws,
    const float* __restrict__ wf1, const float* __restrict__ bf1,
    const float* __restrict__ wf2, const float* __restrict__ bf2,
    float* __restrict__ fused)
{
    __shared__ float s_in[FR][VV * HH];     // 16 x 512 = 32 KB
    __shared__ float s_hid[FR][2 * HH];     // 16 x 256 = 16 KB
    int nbase = blockIdx.x * FR;
    float at[VV];
    #pragma unroll
    for (int v = 0; v < VV; ++v) at[v] = attn_ws[v];

    // stage fusion_in = concat_v(h2[v, n, :] * attn[v]) as float4
    for (int idx = threadIdx.x; idx < FR * VV * HH / 4; idx += 256) {
        int r  = idx >> 7;            // /128 float4 per row
        int c4 = idx & 127;
        int v  = c4 >> 5;
        int h4 = c4 & 31;
        const float4* srcr = (const float4*)(h2 + ((size_t)v * NN + nbase + r) * HH);
        float4 x = srcr[h4];
        float s = at[v];
        x.x *= s; x.y *= s; x.z *= s; x.w *= s;
        ((float4*)&s_in[r][0])[c4] = x;
    }
    __syncthreads();

    // GEMM1: hidden[16x256] = relu(s_in[16x512] @ wf1 + bf1)
    {
        int r0 = (threadIdx.x >> 6) * 4;       // 0..12
        int c0 = (threadIdx.x & 63) * 4;       // 0..252
        float acc[4][4];
        #pragma unroll
        for (int i = 0; i < 4; ++i)
            #pragma unroll
            for (int j = 0; j < 4; ++j) acc[i][j] = 0.f;
        for (int k = 0; k < VV * HH; k += 4) {
            float4 a[4], w[4];
            #pragma unroll
            for (int i = 0; i < 4; ++i) a[i] = *(const float4*)&s_in[r0 + i][k];
            #pragma unroll
            for (int kk = 0; kk < 4; ++kk)
                w[kk] = *(const float4*)&wf1[(size_t)(k + kk) * (2 * HH) + c0];
            #pragma unroll
            for (int i = 0; i < 4; ++i)
                #pragma unroll
                for (int j = 0; j < 4; ++j) {
                    acc[i][j] += a[i].x * ((const float*)&w[0])[j];
                    acc[i][j] += a[i].y * ((const float*)&w[1])[j];
                    acc[i][j] += a[i].z * ((const float*)&w[2])[j];
                    acc[i][j] += a[i].w * ((const float*)&w[3])[j];
                }
        }
        #pragma unroll
        for (int j = 0; j < 4; ++j) {
            float b = bf1[c0 + j];
            #pragma unroll
            for (int i = 0; i < 4; ++i) {
                float hv = acc[i][j] + b;
                s_hid[r0 + i][c0 + j] = hv > 0.f ? hv : 0.f;
            }
        }
    }
    __syncthreads();

    // GEMM2: fused[16x128] = s_hid[16x256] @ wf2 + bf2
    {
        int r0 = (threadIdx.x >> 5) * 2;       // 0..14
        int c0 = (threadIdx.x & 31) * 4;       // 0..124
        float acc[2][4];
        #pragma unroll
        for (int i = 0; i < 2; ++i)
            #pragma unroll
            for (int j = 0; j < 4; ++j) acc[i][j] = 0.f;
        for (int k = 0; k < 2 * HH; k += 4) {
            float4 a[2], w[4];
            #pragma unroll
            for (int i = 0; i < 2; ++i) a[i] = *(const float4*)&s_hid[r0 + i][k];
            #pragma unroll
            for (int kk = 0; kk < 4; ++kk)
                w[kk] = *(const float4*)&wf2[(size_t)(k + kk) * HH + c0];
            #pragma unroll
            for (int i = 0; i < 2; ++i)
                #pragma unroll
                for (int j = 0; j < 4; ++j) {
                    acc[i][j] += a[i].x * ((const float*)&w[0])[j];
                    acc[i][j] += a[i].y * ((const float*)&w[1])[j];
                    acc[i][j] += a[i].z * ((const float*)&w[2])[j];
                    acc[i][j] += a[i].w * ((const float*)&w[3])[j];
                }
        }
        #pragma unroll
        for (int i = 0; i < 2; ++i) {
            float4 o;
            o.x = acc[i][0] + bf2[c0 + 0];
            o.y = acc[i][1] + bf2[c0 + 1];
            o.z = acc[i][2] + bf2[c0 + 2];
            o.w = acc[i][3] + bf2[c0 + 3];
            *(float4*)&fused[(size_t)(nbase + r0 + i) * HH + c0] = o;
        }
    }
}

// ---------------------------------------------------------------------------
extern "C" void kernel_launch(void* const* d_in, const int* in_sizes, int n_in,
                              void* d_out, int out_size, void* d_ws, size_t ws_size,
                              hipStream_t stream)
{
    const float* adjs = (const float*)d_in[0];
    const float* w1   = (const float*)d_in[1];
    const float* b1   = (const float*)d_in[2];
    const float* w2   = (const float*)d_in[3];
    const float* b2   = (const float*)d_in[4];
    const float* wa1  = (const float*)d_in[5];
    const float* ba1  = (const float*)d_in[6];
    const float* wa2  = (const float*)d_in[7];
    const float* ba2  = (const float*)d_in[8];
    const float* wf1  = (const float*)d_in[9];
    const float* bf1  = (const float*)d_in[10];
    const float* wf2  = (const float*)d_in[11];
    const float* bf2  = (const float*)d_in[12];

    float* out   = (float*)d_out;
    float* fused = out;                        // [N, 128]
    float* attn  = out + (size_t)NN * HH;      // [V]
    float* h2    = attn + VV;                  // [V, N, H] (offset mult of 4 -> 16B aligned)

    char* w = (char*)d_ws;
    int*   nbr    = (int*)w;    w += (size_t)VV * NN * CAP * sizeof(int);
    int*   cnt    = (int*)w;    w += (size_t)VV * NN * sizeof(int);
    float* dinv   = (float*)w;  w += (size_t)VV * NN * sizeof(float);
    float* h1     = (float*)w;  w += (size_t)VV * NN * HH * sizeof(float);
    float* t      = (float*)w;  w += (size_t)VV * NN * HH * sizeof(float);
    float* part   = (float*)w;  w += (size_t)VV * CH * HH * sizeof(float);
    float* attnws = (float*)w;  w += (size_t)VV * sizeof(float);

    k_build_csr<<<VV * NN / 4, 256, 0, stream>>>(adjs, nbr, cnt, dinv);
    k_spmm<<<VV * NN, 128, 0, stream>>>(w1, b1, nbr, cnt, dinv, h1);
    k_gemm_w2<<<VV * NN / GR, 256, 0, stream>>>(h1, w2, t);
    k_spmm<<<VV * NN, 128, 0, stream>>>(t, b2, nbr, cnt, dinv, h2);
    k_colsum<<<VV * CH, 128, 0, stream>>>(h2, part);
    k_attn<<<1, 256, 0, stream>>>(part, wa1, ba1, wa2, ba2, attn, attnws);
    k_fusion<<<NN / FR, 256, 0, stream>>>(h2, attnws, wf1, bf1, wf2, bf2, fused);
}